// Round 3
// baseline (94.049 us; speedup 1.0000x reference)
//
#include <hip/hip_runtime.h>
#include <math.h>

// Problem dims (fixed by reference)
#define BDIM 2048
#define ODIM 256
#define IDIM 256
#define NJP  (IDIM / 2)   // 128 j-pairs

// out[b,o] = IDIM + C * sum_j 1/(D - 2at*cos(phi0 + x[b,j] + p[o,j]))
//   C = (t^2-1)(1-a^2),  D = 1+(at)^2
// cos(x'+p) = cos x' cos p - sin x' sin p  =>
//   den = D + (-2at*cos x')*cos p + (2at*sin x')*sin p
//
// Hot-loop data layout (built once by photonic_margins):
//   AmT4[jp][b]        = (mc0, mc1, ms0, ms1)  -- transposed: lane=b coalesced
//       mc = -2at*cos(phi0+x[b][j]), ms = 2at*sin(...), j = 2jp, 2jp+1
//   Pq[g][jp][o4]      = (pc0, pc1, ps0, ps1), g = o>>2, o4 = o&3
//       wave-uniform -> scalar loads (s_load), zero vector-memory cost.
// Main kernel: NO LDS in the j-loop, NO barriers; lane = b, 4 o per lane.

__global__ __launch_bounds__(256)
void photonic_margins(const float* __restrict__ X, const float* __restrict__ P,
                      float4* __restrict__ AmT4, float4* __restrict__ Pq,
                      float phi0, float m2at, float p2at) {
    __shared__ float2 Ls[64][65];
    const int blk = blockIdx.x;
    const int tid = threadIdx.x;
    if (blk < 128) {
        // A-side: transpose+pack one 64b x 64j tile
        const int bb = blk >> 2;   // 0..31  (b-tile)
        const int tt = blk & 3;    // 0..3   (j-tile)
        #pragma unroll
        for (int k = 0; k < 16; ++k) {
            int e = tid + 256 * k;
            int b_l = e >> 6, j_l = e & 63;
            float x = X[(bb * 64 + b_l) * IDIM + tt * 64 + j_l];
            float s, c;
            __sincosf(phi0 + x, &s, &c);
            Ls[j_l][b_l] = make_float2(m2at * c, p2at * s);
        }
        __syncthreads();
        #pragma unroll
        for (int k = 0; k < 8; ++k) {
            int e = tid + 256 * k;
            int jp_l = e >> 6, b_l = e & 63;
            float2 f0 = Ls[2 * jp_l][b_l];
            float2 f1 = Ls[2 * jp_l + 1][b_l];
            AmT4[(size_t)(tt * 32 + jp_l) * BDIM + bb * 64 + b_l] =
                make_float4(f0.x, f1.x, f0.y, f1.y);
        }
    } else {
        // P-side: 256 o x 128 jp, one thread per (o, jp)
        int e = (blk - 128) * 256 + tid;      // 0..32767
        int o = e >> 7, jp = e & 127;
        float p0 = P[o * IDIM + 2 * jp];
        float p1 = P[o * IDIM + 2 * jp + 1];
        float s0, c0, s1, c1;
        __sincosf(p0, &s0, &c0);
        __sincosf(p1, &s1, &c1);
        Pq[(size_t)((o >> 2) * NJP + jp) * 4 + (o & 3)] = make_float4(c0, c1, s0, s1);
    }
}

__device__ __forceinline__ void quad_acc(float d0, float d1, float d2, float d3,
                                         float& acc) {
    // 1/d0+1/d1+1/d2+1/d3 = ((d0+d1)*d23 + (d2+d3)*d01) / (d01*d23)
    float d01 = d0 * d1, d23 = d2 * d3;
    float n = fmaf(d0 + d1, d23, (d2 + d3) * d01);
    acc = fmaf(n, __builtin_amdgcn_rcpf(d01 * d23), acc);
}

__global__ __launch_bounds__(256, 2)
void photonic_main(const float4* __restrict__ AmT4,  // [NJP][BDIM]
                   const float4* __restrict__ Pq,    // [64][NJP][4]
                   float* __restrict__ Out,          // [BDIM][ODIM]
                   float Dc, float Cnum) {
    __shared__ float Ot[64][17];

    const int tid  = threadIdx.x;
    const int lane = tid & 63;
    const int w    = __builtin_amdgcn_readfirstlane(tid >> 6);  // wave id -> SGPR
    const int oc   = blockIdx.x;          // 0..15  (o-cluster of 16)
    const int bb   = blockIdx.y;          // 0..31  (b-group of 64)
    const int g    = oc * 4 + w;          // ogroup (4 o's) 0..63
    const int b    = bb * 64 + lane;

    const float4* __restrict__ av = AmT4 + b;          // stride BDIM per jp
    const float4* __restrict__ pq = Pq + (size_t)g * NJP * 4;

    float acc0 = 0.f, acc1 = 0.f, acc2 = 0.f, acc3 = 0.f;

    #pragma unroll 4
    for (int jp = 0; jp < NJP; jp += 2) {
        float4 va0 = av[(size_t)jp * BDIM];
        float4 va1 = av[(size_t)(jp + 1) * BDIM];
        // wave-uniform scalar loads: 8 float4 = 128 B contiguous
        float4 p00 = pq[jp * 4 + 0];
        float4 p01 = pq[jp * 4 + 1];
        float4 p02 = pq[jp * 4 + 2];
        float4 p03 = pq[jp * 4 + 3];
        float4 p10 = pq[jp * 4 + 4];
        float4 p11 = pq[jp * 4 + 5];
        float4 p12 = pq[jp * 4 + 6];
        float4 p13 = pq[jp * 4 + 7];

        {   // o0: 4 j-terms -> one rcp
            float d0 = fmaf(va0.x, p00.x, fmaf(va0.z, p00.z, Dc));
            float d1 = fmaf(va0.y, p00.y, fmaf(va0.w, p00.w, Dc));
            float d2 = fmaf(va1.x, p10.x, fmaf(va1.z, p10.z, Dc));
            float d3 = fmaf(va1.y, p10.y, fmaf(va1.w, p10.w, Dc));
            quad_acc(d0, d1, d2, d3, acc0);
        }
        {   // o1
            float d0 = fmaf(va0.x, p01.x, fmaf(va0.z, p01.z, Dc));
            float d1 = fmaf(va0.y, p01.y, fmaf(va0.w, p01.w, Dc));
            float d2 = fmaf(va1.x, p11.x, fmaf(va1.z, p11.z, Dc));
            float d3 = fmaf(va1.y, p11.y, fmaf(va1.w, p11.w, Dc));
            quad_acc(d0, d1, d2, d3, acc1);
        }
        {   // o2
            float d0 = fmaf(va0.x, p02.x, fmaf(va0.z, p02.z, Dc));
            float d1 = fmaf(va0.y, p02.y, fmaf(va0.w, p02.w, Dc));
            float d2 = fmaf(va1.x, p12.x, fmaf(va1.z, p12.z, Dc));
            float d3 = fmaf(va1.y, p12.y, fmaf(va1.w, p12.w, Dc));
            quad_acc(d0, d1, d2, d3, acc2);
        }
        {   // o3
            float d0 = fmaf(va0.x, p03.x, fmaf(va0.z, p03.z, Dc));
            float d1 = fmaf(va0.y, p03.y, fmaf(va0.w, p03.w, Dc));
            float d2 = fmaf(va1.x, p13.x, fmaf(va1.z, p13.z, Dc));
            float d3 = fmaf(va1.y, p13.y, fmaf(va1.w, p13.w, Dc));
            quad_acc(d0, d1, d2, d3, acc3);
        }
    }

    // Epilogue: stage 64x16 tile in LDS, write coalesced 64B segments
    const float base = (float)IDIM;
    Ot[lane][w * 4 + 0] = fmaf(Cnum, acc0, base);
    Ot[lane][w * 4 + 1] = fmaf(Cnum, acc1, base);
    Ot[lane][w * 4 + 2] = fmaf(Cnum, acc2, base);
    Ot[lane][w * 4 + 3] = fmaf(Cnum, acc3, base);
    __syncthreads();
    #pragma unroll
    for (int k = 0; k < 4; ++k) {
        int e = tid + 256 * k;
        int b_l = e >> 4, o_l = e & 15;
        Out[(size_t)(bb * 64 + b_l) * ODIM + oc * 16 + o_l] = Ot[b_l][o_l];
    }
}

extern "C" void kernel_launch(void* const* d_in, const int* in_sizes, int n_in,
                              void* d_out, int out_size, void* d_ws, size_t ws_size,
                              hipStream_t stream) {
    const float* X = (const float*)d_in[0];   // input_matrix [2048,256] f32
    const float* P = (const float*)d_in[1];   // phase_offset [256,256] f32
    float* Out = (float*)d_out;               // [2048,256] f32

    // Workspace: AmT4 = 128*2048 float4 (4 MB), Pq = 64*128*4 float4 (0.5 MB)
    float4* AmT4 = (float4*)d_ws;
    float4* Pq   = AmT4 + (size_t)NJP * BDIM;

    const double RADIUS = 5e-6, KAPPA = 0.1, N_EFF = 3.48, LAMBDA = 1.55e-6, LOSS_A = 0.99;
    const double TWO_PI = 6.283185307179586476925286766559;
    const double t  = sqrt(1.0 - KAPPA);
    const double a  = LOSS_A;
    const double at = a * t;
    const double phi0 = fmod(TWO_PI * N_EFF * (TWO_PI * RADIUS) / LAMBDA, TWO_PI);
    const double D    = 1.0 + at * at;
    const double Cnum = (t * t - 1.0) * (1.0 - a * a);   // num - den (constant)

    // Kernel 1: margins (A-side: 128 transpose blocks; P-side: 128 blocks)
    photonic_margins<<<256, 256, 0, stream>>>(
        X, P, AmT4, Pq, (float)phi0, (float)(-2.0 * at), (float)(2.0 * at));

    // Kernel 2: main accumulation — 16 o-clusters x 32 b-groups
    dim3 grid(16, 32);
    photonic_main<<<grid, 256, 0, stream>>>(AmT4, Pq, Out, (float)D, (float)Cnum);
}

// Round 4
// 86.034 us; speedup vs baseline: 1.0932x; 1.0932x over previous
//
#include <hip/hip_runtime.h>
#include <math.h>

// Problem dims (fixed by reference)
#define BDIM 2048
#define ODIM 256
#define IDIM 256
#define NJP  (IDIM / 2)     // 128 j-pairs per row
#define NZ   8              // j-splits
#define JPB  (NJP / NZ)     // 16 j-pairs (32 j) per block
#define PLANE ((size_t)BDIM * ODIM)   // 524288 cells per partial plane

typedef float v2f __attribute__((ext_vector_type(2)));

// out[b,o] = IDIM + C * sum_j 1/(D - 2at*cos(phi0 + x[b,j] + p[o,j]))
//   C = (t^2-1)(1-a^2),  D = 1+(at)^2
// cos(x'+p) = cos x' cos p - sin x' sin p =>
//   den = D + (-2at*cos x')*cos p + (2at*sin x')*sin p
// Margin packing (one float4 per j-pair jp, row-major):
//   AmP[b][jp] = (-2at*c(2jp), -2at*c(2jp+1), 2at*s(2jp), 2at*s(2jp+1)),  c/s of phi0+x
//   PmP[o][jp] = ( c(2jp),      c(2jp+1),     s(2jp),     s(2jp+1))       c/s of p

__global__ __launch_bounds__(256)
void photonic_margins(const float* __restrict__ X, const float* __restrict__ P,
                      float4* __restrict__ AmP, float4* __restrict__ PmP,
                      float phi0, float m2at, float p2at) {
    int e   = blockIdx.x * 256 + threadIdx.x;   // grid covers (BDIM+ODIM)*NJP exactly
    int row = e >> 7;                            // 0..2303
    int jp  = e & (NJP - 1);
    if (row < BDIM) {
        float2 x = *(const float2*)(X + (size_t)row * IDIM + 2 * jp);
        float s0, c0, s1, c1;
        __sincosf(phi0 + x.x, &s0, &c0);
        __sincosf(phi0 + x.y, &s1, &c1);
        AmP[(size_t)row * NJP + jp] = make_float4(m2at * c0, m2at * c1, p2at * s0, p2at * s1);
    } else {
        int r = row - BDIM;
        float2 p = *(const float2*)(P + (size_t)r * IDIM + 2 * jp);
        float s0, c0, s1, c1;
        __sincosf(p.x, &s0, &c0);
        __sincosf(p.y, &s1, &c1);
        PmP[(size_t)r * NJP + jp] = make_float4(c0, c1, s0, s1);
    }
}

__global__ __launch_bounds__(256, 4)
void photonic_main(const float4* __restrict__ AmP,  // [BDIM][NJP]
                   const float4* __restrict__ PmP,  // [ODIM][NJP]
                   float* __restrict__ Pp,          // [NZ][BDIM][ODIM] raw partial sums
                   float Dc) {
    // stride 17 float4 = 272 B = 68 banks % 32 = 4 -> conflict-free read patterns
    __shared__ float4 As[64][17];
    __shared__ float4 Ps[64][17];

    const int tid = threadIdx.x;
    const int tx  = tid & 15;            // o sub-index
    const int ty  = tid >> 4;            // b sub-index
    const int o0  = blockIdx.x * 64;     // 4 o-tiles
    const int b0  = blockIdx.y * 64;     // 32 b-tiles
    const int jp0 = blockIdx.z * JPB;    // 8 j-splits

    // ---- stage margins: 4 float4 per thread per array, coalesced 256B rows ----
    #pragma unroll
    for (int it = 0; it < 4; ++it) {
        int e = tid + 256 * it;
        int r = e >> 4, q = e & 15;
        As[r][q] = AmP[(size_t)(b0 + r) * NJP + jp0 + q];
        Ps[r][q] = PmP[(size_t)(o0 + r) * NJP + jp0 + q];
    }
    __syncthreads();

    float acc[4][4];
    #pragma unroll
    for (int k = 0; k < 4; ++k)
        #pragma unroll
        for (int m = 0; m < 4; ++m) acc[k][m] = 0.f;

    const v2f D2 = {Dc, Dc};

    #pragma unroll 2
    for (int q = 0; q < JPB; q += 2) {
        float4 a[4][2], p[4][2];
        #pragma unroll
        for (int k = 0; k < 4; ++k) {
            a[k][0] = As[ty + 16 * k][q];
            a[k][1] = As[ty + 16 * k][q + 1];
        }
        #pragma unroll
        for (int m = 0; m < 4; ++m) {
            p[m][0] = Ps[tx + 16 * m][q];
            p[m][1] = Ps[tx + 16 * m][q + 1];
        }
        #pragma unroll
        for (int k = 0; k < 4; ++k) {
            #pragma unroll
            for (int m = 0; m < 4; ++m) {
                // 4 j-terms (2 jp) -> one rcp
                v2f ac0 = {a[k][0].x, a[k][0].y}, as0 = {a[k][0].z, a[k][0].w};
                v2f ac1 = {a[k][1].x, a[k][1].y}, as1 = {a[k][1].z, a[k][1].w};
                v2f pc0 = {p[m][0].x, p[m][0].y}, ps0 = {p[m][0].z, p[m][0].w};
                v2f pc1 = {p[m][1].x, p[m][1].y}, ps1 = {p[m][1].z, p[m][1].w};
                v2f d01 = __builtin_elementwise_fma(ac0, pc0,
                          __builtin_elementwise_fma(as0, ps0, D2));
                v2f d23 = __builtin_elementwise_fma(ac1, pc1,
                          __builtin_elementwise_fma(as1, ps1, D2));
                // 1/d0+1/d1+1/d2+1/d3 = ((d0+d1)*p23 + (d2+d3)*p01) / (p01*p23)
                float p01 = d01.x * d01.y, p23 = d23.x * d23.y;
                float n = fmaf(d01.x + d01.y, p23, (d23.x + d23.y) * p01);
                acc[k][m] = fmaf(n, __builtin_amdgcn_rcpf(p01 * p23), acc[k][m]);
            }
        }
    }

    // ---- write raw partial sums (disjoint region per block; no init needed) ----
    float* __restrict__ plane = Pp + (size_t)blockIdx.z * PLANE;
    #pragma unroll
    for (int k = 0; k < 4; ++k)
        #pragma unroll
        for (int m = 0; m < 4; ++m)
            plane[(size_t)(b0 + ty + 16 * k) * ODIM + (o0 + tx + 16 * m)] = acc[k][m];
}

__global__ __launch_bounds__(256)
void photonic_reduce(const float* __restrict__ Pp,  // [NZ][BDIM][ODIM]
                     float* __restrict__ Out,       // [BDIM][ODIM]
                     float Cnum) {
    size_t i = (size_t)blockIdx.x * 256 + threadIdx.x;   // grid covers PLANE exactly
    float s = 0.f;
    #pragma unroll
    for (int z = 0; z < NZ; ++z) s += Pp[z * PLANE + i];
    Out[i] = fmaf(Cnum, s, (float)IDIM);
}

extern "C" void kernel_launch(void* const* d_in, const int* in_sizes, int n_in,
                              void* d_out, int out_size, void* d_ws, size_t ws_size,
                              hipStream_t stream) {
    const float* X = (const float*)d_in[0];   // input_matrix [2048,256] f32
    const float* P = (const float*)d_in[1];   // phase_offset [256,256] f32
    float* Out = (float*)d_out;               // [2048,256] f32

    // Workspace: AmP 4 MB, PmP 0.5 MB, Pp 16 MB
    float4* AmP = (float4*)d_ws;
    float4* PmP = AmP + (size_t)BDIM * NJP;
    float*  Pp  = (float*)(PmP + (size_t)ODIM * NJP);

    const double RADIUS = 5e-6, KAPPA = 0.1, N_EFF = 3.48, LAMBDA = 1.55e-6, LOSS_A = 0.99;
    const double TWO_PI = 6.283185307179586476925286766559;
    const double t  = sqrt(1.0 - KAPPA);
    const double a  = LOSS_A;
    const double at = a * t;
    const double phi0 = fmod(TWO_PI * N_EFF * (TWO_PI * RADIUS) / LAMBDA, TWO_PI);
    const double D    = 1.0 + at * at;
    const double Cnum = (t * t - 1.0) * (1.0 - a * a);   // num - den (constant)

    // Kernel 1: margins — (2048+256) rows x 128 jp = 294912 threads
    photonic_margins<<<(BDIM + ODIM) * NJP / 256, 256, 0, stream>>>(
        X, P, AmP, PmP, (float)phi0, (float)(-2.0 * at), (float)(2.0 * at));

    // Kernel 2: main — 4 o-tiles x 32 b-tiles x 8 j-splits = 1024 blocks (4/CU)
    dim3 grid(ODIM / 64, BDIM / 64, NZ);
    photonic_main<<<grid, 256, 0, stream>>>(AmP, PmP, Pp, (float)D);

    // Kernel 3: reduce partials -> Out
    photonic_reduce<<<PLANE / 256, 256, 0, stream>>>(Pp, Out, (float)Cnum);
}